// Round 1
// baseline (618.257 us; speedup 1.0000x reference)
//
#include <hip/hip_runtime.h>
#include <math.h>

typedef __attribute__((ext_vector_type(8))) short bf16x8;
typedef __attribute__((ext_vector_type(4))) float f32x4;
typedef __attribute__((ext_vector_type(4))) short s16x4;

#define NBATCH 4
#define NPTS   4096
#define NTOT   (NBATCH*NPTS)   // 16384

__device__ __forceinline__ float bf2f(unsigned short h){
  unsigned int u = ((unsigned int)h) << 16;
  return __builtin_bit_cast(float, u);
}
__device__ __forceinline__ unsigned short f2bf(float f){
  unsigned int u = __builtin_bit_cast(unsigned int, f);
  u += 0x7FFFu + ((u >> 16) & 1u);   // RNE
  return (unsigned short)(u >> 16);
}

// byte offset into a [row][256 bf16] LDS tile (512B row stride), XOR-swizzled
// to kill the 512B-stride bank conflict. kbyte in [0,512), 16B-block safe.
__device__ __forceinline__ unsigned int swz(int row, int kbyte){
  return (unsigned int)(row * 512) + (((unsigned int)kbyte) ^ (((unsigned int)row & 7u) << 4));
}

// ---------------- prep: features -> bf16 ----------------
__global__ __launch_bounds__(256) void k_convert(const float* __restrict__ x,
                                                 unsigned short* __restrict__ xb, int n){
  int i = (blockIdx.x * 256 + threadIdx.x) * 4;
  if (i < n){
    float4 v = *(const float4*)(x + i);
    s16x4 o;
    o[0] = (short)f2bf(v.x); o[1] = (short)f2bf(v.y);
    o[2] = (short)f2bf(v.z); o[3] = (short)f2bf(v.w);
    *(s16x4*)(xb + i) = o;
  }
}

// ---------------- prep: transposed bf16 weight copies ----------------
__global__ __launch_bounds__(256) void k_prep_mats(
    const float* __restrict__ fc1w, const float* __restrict__ scw,
    const float* __restrict__ wv,  const float* __restrict__ g2,
    const float* __restrict__ fc2, const float* __restrict__ W2,
    unsigned short* __restrict__ fc1scT, unsigned short* __restrict__ qkvT,
    unsigned short* __restrict__ g2sT, unsigned short* __restrict__ fc2T,
    unsigned short* __restrict__ BposT){
  int c = blockIdx.x, d = threadIdx.x;
  fc1scT[c*256 + d]       = f2bf(fc1w[d*256 + c]);
  fc1scT[(256+c)*256 + d] = f2bf(scw[d*256 + c]);
  qkvT[(512+c)*256 + d]   = f2bf(wv[d*256 + c]);
  g2sT[c*256 + d]         = f2bf(g2[d*256 + c] * 0.0625f);   // fold 1/sqrt(DM)=1/16
  fc2T[c*256 + d]         = f2bf(fc2[d*256 + c]);
  BposT[(256+c)*256 + d]  = f2bf(W2[d*256 + c]);
}

// ---------------- prep: folded weight GEMMs (256x256x256, tiny) ----------------
__global__ __launch_bounds__(256) void k_prep_gemm(
    const float* __restrict__ wq, const float* __restrict__ wk,
    const float* __restrict__ g1, const float* __restrict__ W2,
    const float* __restrict__ b2d, const float* __restrict__ gb1,
    unsigned short* __restrict__ qkvT, unsigned short* __restrict__ BposT,
    float* __restrict__ c1){
  int c = threadIdx.x, bid = blockIdx.x;
  if (bid < 256){                       // WqgT[c][d] = sum_e wq[d][e] g1[e][c]
    int d = bid; float acc = 0.f;
    for (int e=0;e<256;e++) acc += wq[d*256+e]*g1[e*256+c];
    qkvT[c*256 + d] = f2bf(acc);
  } else if (bid < 512){                // WkgT
    int d = bid-256; float acc = 0.f;
    for (int e=0;e<256;e++) acc += wk[d*256+e]*g1[e*256+c];
    qkvT[(256+c)*256 + d] = f2bf(acc);
  } else if (bid < 768){                // W2g1T -> BposT rows 0..255
    int d = bid-512; float acc = 0.f;
    for (int e=0;e<256;e++) acc += W2[d*256+e]*g1[e*256+c];
    BposT[c*256 + d] = f2bf(acc);
  } else {                              // c1 = b2d @ g1 + gb1
    float acc = 0.f;
    for (int e=0;e<256;e++) acc += b2d[e]*g1[e*256+c];
    c1[c] = acc + gb1[c];
  }
}

// ---------------- kNN: one wave per point, per-lane top16 + merge ----------------
__global__ __launch_bounds__(256) void k_knn(const float* __restrict__ xyz,
                                             int* __restrict__ knn){
  int wave = threadIdx.x >> 6, lane = threadIdx.x & 63;
  int widx = blockIdx.x * 4 + wave;           // 0..16383
  int b = widx >> 12, n = widx & 4095;
  const float* xb = xyz + (size_t)b * NPTS * 3;
  float px = xb[n*3+0], py = xb[n*3+1], pz = xb[n*3+2];
  float x2n = px*px + py*py + pz*pz;
  float dist[16]; int didx[16];
  #pragma unroll
  for (int i=0;i<16;i++){ dist[i] = 3.4e38f; didx[i] = -1; }
  float cmax = 3.4e38f; int cslot = 0;
  for (int t=0;t<64;t++){
    int m = t*64 + lane;                      // lanes own disjoint candidate sets
    float qx = xb[m*3+0], qy = xb[m*3+1], qz = xb[m*3+2];
    float x2m = qx*qx + qy*qy + qz*qz;
    float dot = px*qx + py*qy + pz*qz;
    float d = x2n + x2m - 2.0f*dot;           // same formula as reference
    if (d < cmax){
      dist[cslot] = d; didx[cslot] = m;
      cmax = dist[0]; cslot = 0;
      #pragma unroll
      for (int i=1;i<16;i++) if (dist[i] > cmax){ cmax = dist[i]; cslot = i; }
    }
  }
  int keep = -1;
  for (int r=0;r<16;r++){
    float lv = dist[0]; int li = didx[0], ls = 0;
    #pragma unroll
    for (int i=1;i<16;i++)
      if (dist[i] < lv || (dist[i] == lv && didx[i] < li)){ lv = dist[i]; li = didx[i]; ls = i; }
    float gv = lv; int gi = li;
    #pragma unroll
    for (int off=32; off>=1; off>>=1){
      float ov = __shfl_xor(gv, off, 64);
      int   oi = __shfl_xor(gi, off, 64);
      if (ov < gv || (ov == gv && oi < gi)){ gv = ov; gi = oi; }
    }
    if (gi == li) dist[ls] = 3.4e38f;        // owner pops (indices unique per lane)
    if (lane == r) keep = gi;
  }
  if (lane < 16) knn[(size_t)widx*16 + lane] = keep;
}

// ---------------- flat GEMM: C(16384 x N) = A(16384x256,bf16) @ BT^T ----------------
// MODE 0: B1  N=512  -> out0=f(+fc1_b,bf16), out1=sc(+sc_b,bf16)
// MODE 1: B2  N=768  -> out0=qg, out1=kg, out2=v  (bf16, no bias)
// MODE 2: D   N=256  -> fout = acc + fc2_b + sc (fp32 final output)
template<int MODE>
__global__ __launch_bounds__(256) void k_gemm(
    const unsigned short* __restrict__ A, const unsigned short* __restrict__ BT,
    const float* __restrict__ bias0, const float* __restrict__ bias1,
    unsigned short* __restrict__ out0, unsigned short* __restrict__ out1,
    unsigned short* __restrict__ out2, const unsigned short* __restrict__ scbuf,
    float* __restrict__ fout){
  __shared__ unsigned short As[128*40];   // 32k + 8 pad -> 80B stride, conflict-free
  __shared__ unsigned short Bs[128*40];
  int m0 = blockIdx.x * 128, n0 = blockIdx.y * 128;
  int t = threadIdx.x;
  int lane = t & 63, wave = t >> 6, wm = wave >> 1, wn = wave & 1;
  int lrow = lane & 15, lkg = lane >> 4;
  f32x4 acc[4][4] = {};
  for (int k0 = 0; k0 < 256; k0 += 32){
    int r = t >> 1, h = t & 1;
    const bf16x8* ga = (const bf16x8*)(A  + (size_t)(m0 + r)*256 + k0 + h*16);
    const bf16x8* gb = (const bf16x8*)(BT + (size_t)(n0 + r)*256 + k0 + h*16);
    bf16x8 a0 = ga[0], a1 = ga[1], b0 = gb[0], b1 = gb[1];
    *(bf16x8*)&As[r*40 + h*16]     = a0;
    *(bf16x8*)&As[r*40 + h*16 + 8] = a1;
    *(bf16x8*)&Bs[r*40 + h*16]     = b0;
    *(bf16x8*)&Bs[r*40 + h*16 + 8] = b1;
    __syncthreads();
    bf16x8 af[4], bfr[4];
    #pragma unroll
    for (int fi=0; fi<4; fi++){
      af[fi]  = *(const bf16x8*)&As[(wm*64 + fi*16 + lrow)*40 + lkg*8];
      bfr[fi] = *(const bf16x8*)&Bs[(wn*64 + fi*16 + lrow)*40 + lkg*8];
    }
    #pragma unroll
    for (int fi=0; fi<4; fi++)
      #pragma unroll
      for (int nf=0; nf<4; nf++)
        acc[fi][nf] = __builtin_amdgcn_mfma_f32_16x16x32_bf16(af[fi], bfr[nf], acc[fi][nf], 0,0,0);
    __syncthreads();
  }
  #pragma unroll
  for (int fi=0; fi<4; fi++)
    #pragma unroll
    for (int nf=0; nf<4; nf++)
      #pragma unroll
      for (int r=0; r<4; r++){
        int row = m0 + wm*64 + fi*16 + lkg*4 + r;       // C/D: col=lane&15, row=(lane>>4)*4+reg
        int col = n0 + wn*64 + nf*16 + lrow;
        float v = acc[fi][nf][r];
        if (MODE == 0){
          if (col < 256) out0[(size_t)row*256 + col]       = f2bf(v + bias0[col]);
          else           out1[(size_t)row*256 + col - 256] = f2bf(v + bias1[col-256]);
        } else if (MODE == 1){
          if (col < 256)      out0[(size_t)row*256 + col]       = f2bf(v);
          else if (col < 512) out1[(size_t)row*256 + col - 256] = f2bf(v);
          else                out2[(size_t)row*256 + col - 512] = f2bf(v);
        } else {
          fout[(size_t)row*256 + col] = v + bias0[col] + bf2f(scbuf[(size_t)row*256 + col]);
        }
      }
}

// ---------------- stage C: fused per-point transformer core ----------------
// WG = 512 thr (8 waves), 8 points -> M=128 rows (point-major, 16 nbrs each).
// wave w owns 32 output cols [32w, 32w+32).
__global__ __launch_bounds__(512) void k_stagec(
    const float* __restrict__ xyz, const int* __restrict__ knn,
    const unsigned short* __restrict__ qgbuf, const unsigned short* __restrict__ kgbuf,
    const unsigned short* __restrict__ vbuf,
    const unsigned short* __restrict__ BposT, const unsigned short* __restrict__ g2sT,
    const float* __restrict__ W1, const float* __restrict__ b1d,
    const float* __restrict__ b2d, const float* __restrict__ c1,
    const float* __restrict__ gb2,
    unsigned short* __restrict__ resbuf){
  extern __shared__ char smem[];
  unsigned short* Hs  = (unsigned short*)(smem);            // 64KB, swizzled
  unsigned short* A2s = (unsigned short*)(smem + 65536);    // 64KB, swizzled
  unsigned short* qgs = (unsigned short*)(smem + 131072);   // 8x256 bf16
  float* rels = (float*)(smem + 135168);                    // 128x4
  float* W1s  = (float*)(smem + 137216);                    // 3x256
  float* b1s  = (float*)(smem + 140288);
  float* c1s  = (float*)(smem + 141312);
  float* b2s  = (float*)(smem + 142336);
  float* gb2s = (float*)(smem + 143360);
  int*   gidx = (int*)(smem + 144384);                      // 128 ints
  float* resS = (float*)(smem + 144896);                    // 8x256 fp32

  int t = threadIdx.x;
  int lane = t & 63, wn = t >> 6;         // 8 waves, 32 cols each
  int lrow = lane & 15, lkg = lane >> 4;
  int tile = blockIdx.x;                  // 2048 tiles
  int b = tile >> 9;
  int n0 = (tile & 511) * 8;
  int g0 = b*NPTS + n0;

  // ---- phase 0: stage small data ----
  for (int i = t; i < 768; i += 512) W1s[i] = W1[i];
  if (t < 256){ b1s[t] = b1d[t]; c1s[t] = c1[t]; b2s[t] = b2d[t]; gb2s[t] = gb2[t]*0.0625f; }
  if (t < 128){
    int p = t >> 4, kk = t & 15;
    int id = knn[(size_t)(g0 + p)*16 + kk];
    gidx[t] = b*NPTS + id;
    const float* cp = xyz + (size_t)(b*NPTS + n0 + p)*3;
    const float* np_ = xyz + (size_t)(b*NPTS + id)*3;
    rels[t*4+0] = cp[0]-np_[0]; rels[t*4+1] = cp[1]-np_[1]; rels[t*4+2] = cp[2]-np_[2];
  }
  { // qg rows for the 8 points
    int e = t * 4; int p = e >> 8, c = e & 255;
    *(s16x4*)&qgs[e] = *(const s16x4*)&qgbuf[(size_t)(g0 + p)*256 + c];
  }
  __syncthreads();

  // ---- phase 1: H = relu(rel @ W1 + b1)  (bf16, swizzled LDS) ----
  {
    int r = t >> 2, c0 = (t & 3) * 64;
    float rx = rels[r*4], ry = rels[r*4+1], rz = rels[r*4+2];
    for (int cc = 0; cc < 64; cc += 8){
      int c = c0 + cc;
      bf16x8 hv;
      #pragma unroll
      for (int j=0;j<8;j++){
        float h = rx*W1s[c+j] + ry*W1s[256+c+j] + rz*W1s[512+c+j] + b1s[c+j];
        hv[j] = (short)f2bf(fmaxf(h, 0.0f));
      }
      *(bf16x8*)((char*)Hs + swz(r, c*2)) = hv;
    }
  }
  __syncthreads();

  // ---- phase 2: GEMM1 fused: [posg | pe] = H @ [W2g1 | W2] ----
  f32x4 accg[8][2] = {}, acce[8][2] = {};
  for (int k0 = 0; k0 < 256; k0 += 32){
    bf16x8 af[8];
    #pragma unroll
    for (int fi=0; fi<8; fi++)
      af[fi] = *(const bf16x8*)((const char*)Hs + swz(fi*16 + lrow, k0*2 + lkg*16));
    bf16x8 bg[2], be[2];
    #pragma unroll
    for (int nf=0; nf<2; nf++){
      int ng = 32*wn + nf*16 + lrow;
      bg[nf] = *(const bf16x8*)(BposT + (size_t)ng*256 + k0 + lkg*8);
      be[nf] = *(const bf16x8*)(BposT + (size_t)(256+ng)*256 + k0 + lkg*8);
    }
    #pragma unroll
    for (int fi=0; fi<8; fi++){
      accg[fi][0] = __builtin_amdgcn_mfma_f32_16x16x32_bf16(af[fi], bg[0], accg[fi][0], 0,0,0);
      accg[fi][1] = __builtin_amdgcn_mfma_f32_16x16x32_bf16(af[fi], bg[1], accg[fi][1], 0,0,0);
      acce[fi][0] = __builtin_amdgcn_mfma_f32_16x16x32_bf16(af[fi], be[0], acce[fi][0], 0,0,0);
      acce[fi][1] = __builtin_amdgcn_mfma_f32_16x16x32_bf16(af[fi], be[1], acce[fi][1], 0,0,0);
    }
  }
  // epilogue: A2 = bf16(relu(posg + qg - kg[idx] + c1)) ; pe += b2
  #pragma unroll
  for (int fi=0; fi<8; fi++)
    #pragma unroll
    for (int nf=0; nf<2; nf++)
      #pragma unroll
      for (int r=0; r<4; r++){
        int row = fi*16 + lkg*4 + r;
        int col = 32*wn + nf*16 + lrow;
        float a1 = accg[fi][nf][r]
                 + bf2f(qgs[fi*256 + col])
                 - bf2f(kgbuf[(size_t)gidx[row]*256 + col])
                 + c1s[col];
        *(unsigned short*)((char*)A2s + swz(row, col*2)) = f2bf(fmaxf(a1, 0.0f));
        acce[fi][nf][r] = acce[fi][nf][r] + b2s[col];
      }
  __syncthreads();

  // ---- phase 3: GEMM2: s = relu(a1) @ (g2/16) ----
  f32x4 acc2[8][2] = {};
  for (int k0 = 0; k0 < 256; k0 += 32){
    bf16x8 af[8];
    #pragma unroll
    for (int fi=0; fi<8; fi++)
      af[fi] = *(const bf16x8*)((const char*)A2s + swz(fi*16 + lrow, k0*2 + lkg*16));
    bf16x8 b2f[2];
    #pragma unroll
    for (int nf=0; nf<2; nf++){
      int ng = 32*wn + nf*16 + lrow;
      b2f[nf] = *(const bf16x8*)(g2sT + (size_t)ng*256 + k0 + lkg*8);
    }
    #pragma unroll
    for (int fi=0; fi<8; fi++){
      acc2[fi][0] = __builtin_amdgcn_mfma_f32_16x16x32_bf16(af[fi], b2f[0], acc2[fi][0], 0,0,0);
      acc2[fi][1] = __builtin_amdgcn_mfma_f32_16x16x32_bf16(af[fi], b2f[1], acc2[fi][1], 0,0,0);
    }
  }
  // ---- phase 4: softmax over K=16 (rows of each fragment) + res ----
  #pragma unroll
  for (int fi=0; fi<8; fi++)
    #pragma unroll
    for (int nf=0; nf<2; nf++){
      int col = 32*wn + nf*16 + lrow;
      float s[4], e[4];
      #pragma unroll
      for (int r=0;r<4;r++) s[r] = acc2[fi][nf][r] + gb2s[col];
      float mx = fmaxf(fmaxf(s[0],s[1]), fmaxf(s[2],s[3]));
      mx = fmaxf(mx, __shfl_xor(mx, 16, 64));
      mx = fmaxf(mx, __shfl_xor(mx, 32, 64));
      float sm = 0.f;
      #pragma unroll
      for (int r=0;r<4;r++){ e[r] = __expf(s[r]-mx); sm += e[r]; }
      sm += __shfl_xor(sm, 16, 64);
      sm += __shfl_xor(sm, 32, 64);
      float rs = 1.0f / sm;
      float tsum = 0.f;
      #pragma unroll
      for (int r=0;r<4;r++){
        int row = fi*16 + lkg*4 + r;
        float vv = bf2f(vbuf[(size_t)gidx[row]*256 + col]) + acce[fi][nf][r];
        tsum += (e[r]*rs) * vv;
      }
      tsum += __shfl_xor(tsum, 16, 64);
      tsum += __shfl_xor(tsum, 32, 64);
      if (lkg == 0) resS[fi*256 + col] = tsum;
    }
  __syncthreads();

  // ---- phase 5: store res (bf16) ----
  {
    int e = t * 4; int p = e >> 8, c = e & 255;
    float4 v = *(float4*)&resS[e];
    s16x4 o;
    o[0] = (short)f2bf(v.x); o[1] = (short)f2bf(v.y);
    o[2] = (short)f2bf(v.z); o[3] = (short)f2bf(v.w);
    *(s16x4*)&resbuf[(size_t)(g0 + p)*256 + c] = o;
  }
}

// ---------------- host ----------------
extern "C" void kernel_launch(void* const* d_in, const int* in_sizes, int n_in,
                              void* d_out, int out_size, void* d_ws, size_t ws_size,
                              hipStream_t stream){
  (void)in_sizes; (void)n_in; (void)out_size; (void)ws_size;
  const float* xyz  = (const float*)d_in[0];
  const float* feat = (const float*)d_in[1];
  const float* W1   = (const float*)d_in[2];
  const float* b1d  = (const float*)d_in[3];
  const float* W2   = (const float*)d_in[4];
  const float* b2d  = (const float*)d_in[5];
  const float* fc1w = (const float*)d_in[6];
  const float* fc1b = (const float*)d_in[7];
  const float* wq   = (const float*)d_in[8];
  const float* wk   = (const float*)d_in[9];
  const float* wv   = (const float*)d_in[10];
  const float* g1   = (const float*)d_in[11];
  const float* gb1  = (const float*)d_in[12];
  const float* g2   = (const float*)d_in[13];
  const float* gb2  = (const float*)d_in[14];
  const float* fc2w = (const float*)d_in[15];
  const float* fc2b = (const float*)d_in[16];
  const float* scw  = (const float*)d_in[17];
  const float* scb  = (const float*)d_in[18];

  char* ws = (char*)d_ws;
  size_t off = 0;
  auto alloc = [&](size_t bytes)->void*{ void* p = ws + off; off += (bytes + 255) & ~(size_t)255; return p; };
  int*            knn    = (int*)alloc((size_t)NTOT*16*4);
  unsigned short* Xb     = (unsigned short*)alloc((size_t)NTOT*256*2); // reused as res
  unsigned short* fbuf   = (unsigned short*)alloc((size_t)NTOT*256*2);
  unsigned short* qg     = (unsigned short*)alloc((size_t)NTOT*256*2);
  unsigned short* kg     = (unsigned short*)alloc((size_t)NTOT*256*2);
  unsigned short* vbuf   = (unsigned short*)alloc((size_t)NTOT*256*2);
  unsigned short* scbuf  = (unsigned short*)alloc((size_t)NTOT*256*2);
  unsigned short* fc1scT = (unsigned short*)alloc(512*256*2);
  unsigned short* qkvT   = (unsigned short*)alloc(768*256*2);
  unsigned short* BposT  = (unsigned short*)alloc(512*256*2);
  unsigned short* g2sT   = (unsigned short*)alloc(256*256*2);
  unsigned short* fc2T   = (unsigned short*)alloc(256*256*2);
  float*          c1     = (float*)alloc(256*4);
  unsigned short* res    = Xb;   // alias: Xb dead after B1

  k_convert<<<4096, 256, 0, stream>>>(feat, Xb, NTOT*256);
  k_prep_mats<<<256, 256, 0, stream>>>(fc1w, scw, wv, g2, fc2w, W2, fc1scT, qkvT, g2sT, fc2T, BposT);
  k_prep_gemm<<<769, 256, 0, stream>>>(wq, wk, g1, W2, b2d, gb1, qkvT, BposT, c1);
  k_knn<<<4096, 256, 0, stream>>>(xyz, knn);
  k_gemm<0><<<dim3(128,4), 256, 0, stream>>>(Xb, fc1scT, fc1b, scb, fbuf, scbuf, nullptr, nullptr, nullptr);
  k_gemm<1><<<dim3(128,6), 256, 0, stream>>>(fbuf, qkvT, nullptr, nullptr, qg, kg, vbuf, nullptr, nullptr);
  hipFuncSetAttribute((const void*)k_stagec, hipFuncAttributeMaxDynamicSharedMemorySize, 153088);
  k_stagec<<<2048, 512, 153088, stream>>>(xyz, knn, qg, kg, vbuf, BposT, g2sT, W1, b1d, b2d, c1, gb2, res);
  k_gemm<2><<<dim3(128,2), 256, 0, stream>>>(res, fc2T, fc2b, nullptr, nullptr, nullptr, nullptr, scbuf, (float*)d_out);
}